// Round 4
// baseline (202.909 us; speedup 1.0000x reference)
//
#include <hip/hip_runtime.h>

// LIF constants (match reference)
constexpr int   SEQ      = 100;
constexpr float DT_TAUI  = 0.1f;   // DT * TAU_MEM_INV
constexpr float V_TH     = 1.0f;

typedef float f32x2 __attribute__((ext_vector_type(2)));
typedef float f32x4 __attribute__((ext_vector_type(4)));

// R3 structure (2048 consecutive neurons/block, 2x f32x4 cached stores per
// plane, 1 block/CU), with ONE change: planes are written t=99 -> 0.
// Theory: the harness's 800 MiB re-poison fill precedes us in-stream and
// its tail (~highest addresses) is still dirty-resident in L2/L3 when we
// start. Descending-t overwrites those lines while resident, canceling
// their poison writeback (one HBM write instead of two). Simulation still
// runs t ascending (registers); we buffer all 100 plane-values... that
// would need 100 regs/lane -- instead we simulate fully per plane batch:
// simulation is ~free (24 VALU/plane), so we just simulate forward and
// store into a per-thread 100-entry... ALSO too big. Resolution: exploit
// linearity -- run the sim forward twice: once to... no. Simplest exact
// scheme: simulate forward, store planes ascending BUT start at the high
// half: write planes 50..99 first (forward sim pass 1 discarding t<50
// stores is wrong -- stores needed). Final scheme: two forward sim passes:
// pass A simulates t=0..99 storing only t>=50 (high half first), pass B
// re-simulates t=0..49 storing them. Sim cost is negligible; store order
// becomes high-half-then-low-half, capturing most of the cancellation win.
__global__ __launch_bounds__(256) void lif_encode_wide(
    const float* __restrict__ in, float* __restrict__ out, int n)
{
    int tid   = threadIdx.x;
    int base4 = (blockIdx.x << 9) + tid;          // f32x4 index of group A

    const f32x4* in4 = reinterpret_cast<const f32x4*>(in);
    f32x4 Ia = in4[base4];
    f32x4 Ib = in4[base4 + 256];

    int step4 = n >> 2;                           // one plane, in f32x4 units

    // Pass A: simulate t=0..99, store only planes t >= 50 (high addresses,
    // freshest poison lines, overwritten first while still L3-resident).
    // Pass B: re-simulate t=0..49 and store them.
#pragma unroll
    for (int pass = 0; pass < 2; ++pass) {
        const int t_lo    = (pass == 0) ? 0  : 0;
        const int t_hi    = (pass == 0) ? SEQ : 50;
        const int t_store = (pass == 0) ? 50 : 0;

        f32x4 va = {0.f, 0.f, 0.f, 0.f};
        f32x4 vb = {0.f, 0.f, 0.f, 0.f};
        f32x4* outA = reinterpret_cast<f32x4*>(out) + base4
                    + (size_t)t_lo * step4;

        for (int t = t_lo; t < t_hi; ++t) {
            f32x4 za, zb;
#pragma unroll
            for (int c = 0; c < 4; ++c) {
                va[c] += DT_TAUI * (Ia[c] - va[c]);
                vb[c] += DT_TAUI * (Ib[c] - vb[c]);
                float sza = (va[c] > V_TH) ? 1.f : 0.f;
                float szb = (vb[c] > V_TH) ? 1.f : 0.f;
                za[c] = sza;
                zb[c] = szb;
                va[c] = (sza != 0.f) ? 0.f : va[c];
                vb[c] = (szb != 0.f) ? 0.f : vb[c];
            }
            if (t >= t_store) {
                outA[0]   = za;
                outA[256] = zb;
            }
            outA += step4;
        }
    }
}

// Fallback: round-0 kernel (2 neurons/thread, cached 8B stores)
__global__ __launch_bounds__(256) void lif_encode_kernel(
    const float* __restrict__ in, float* __restrict__ out, int n2)
{
    int i = blockIdx.x * blockDim.x + threadIdx.x;
    if (i >= n2) return;

    const f32x2* in2  = reinterpret_cast<const f32x2*>(in);
    f32x2*       out2 = reinterpret_cast<f32x2*>(out);

    f32x2 I = in2[i];
    f32x2 v = {0.f, 0.f};

    for (int t = 0; t < SEQ; ++t) {
        v.x += DT_TAUI * (I.x - v.x);
        v.y += DT_TAUI * (I.y - v.y);
        f32x2 z;
        z.x = (v.x > V_TH) ? 1.f : 0.f;
        z.y = (v.y > V_TH) ? 1.f : 0.f;
        v.x -= z.x * v.x;
        v.y -= z.y * v.y;
        out2[(size_t)t * n2 + i] = z;
    }
}

extern "C" void kernel_launch(void* const* d_in, const int* in_sizes, int n_in,
                              void* d_out, int out_size, void* d_ws, size_t ws_size,
                              hipStream_t stream)
{
    const float* in  = reinterpret_cast<const float*>(d_in[0]);
    float*       out = reinterpret_cast<float*>(d_out);
    int n = in_sizes[0];               // 64*8192 = 524288 neurons

    if ((n & 2047) == 0) {
        int grid = n >> 11;            // 2048 neurons per block -> 256
        lif_encode_wide<<<grid, 256, 0, stream>>>(in, out, n);
    } else {
        int n2 = n / 2;
        int block = 256;
        int grid  = (n2 + block - 1) / block;
        lif_encode_kernel<<<grid, block, 0, stream>>>(in, out, n2);
    }
}

// Round 5
// 194.874 us; speedup vs baseline: 1.0412x; 1.0412x over previous
//
#include <hip/hip_runtime.h>

// LIF constants (match reference)
constexpr int   SEQ      = 100;
constexpr float DT_TAUI  = 0.1f;   // DT * TAU_MEM_INV
constexpr float V_TH     = 1.0f;

typedef float f32x2 __attribute__((ext_vector_type(2)));

// FINAL (revert to best-measured R0 structure, 196.9 us end-to-end).
//
// Session conclusion: the timed window is bus-conserved:
//   ~127 us  harness poison fill (800 MiB @ 6.6 TB/s = demonstrated ceiling)
//   ~ 70 us  kernel = (200 MiB output + ~256 MiB residual poison drain) / 6.6 TB/s
// Five structural variants (cached 2KB-sliver stores / nt stores / two-pass
// linear expansion / 8KB-chunk f32x4 stores / reordered stores) all measured
// 70-80 us for the kernel portion -> store-path structure is a null lever;
// the limiter is total HBM write traffic, not kernel structure. Compute is
// ~free (VALUBusy ~5-10%). This simplest variant was the fastest measured.
__global__ __launch_bounds__(256) void lif_encode_kernel(
    const float* __restrict__ in, float* __restrict__ out, int n2)
{
    int i = blockIdx.x * blockDim.x + threadIdx.x;
    if (i >= n2) return;

    const f32x2* in2  = reinterpret_cast<const f32x2*>(in);
    f32x2*       out2 = reinterpret_cast<f32x2*>(out);

    f32x2 I = in2[i];
    f32x2 v = {0.f, 0.f};

    for (int t = 0; t < SEQ; ++t) {
        // v' = v + 0.1*(I - v)
        v.x += DT_TAUI * (I.x - v.x);
        v.y += DT_TAUI * (I.y - v.y);
        // z = H(v' - v_th); v'' = v' - z*(v' - v_reset), v_reset = 0
        f32x2 z;
        z.x = (v.x > V_TH) ? 1.f : 0.f;
        z.y = (v.y > V_TH) ? 1.f : 0.f;
        v.x -= z.x * v.x;
        v.y -= z.y * v.y;
        out2[(size_t)t * n2 + i] = z;
    }
}

extern "C" void kernel_launch(void* const* d_in, const int* in_sizes, int n_in,
                              void* d_out, int out_size, void* d_ws, size_t ws_size,
                              hipStream_t stream)
{
    const float* in  = reinterpret_cast<const float*>(d_in[0]);
    float*       out = reinterpret_cast<float*>(d_out);
    int n  = in_sizes[0];      // 64*8192 = 524288
    int n2 = n / 2;            // 262144 threads
    int block = 256;
    int grid  = (n2 + block - 1) / block;   // 1024
    lif_encode_kernel<<<grid, block, 0, stream>>>(in, out, n2);
}